// Round 1
// baseline (227.824 us; speedup 1.0000x reference)
//
#include <hip/hip_runtime.h>
#include <hip/hip_bf16.h>

typedef short short8 __attribute__((ext_vector_type(8)));
typedef float f32x4 __attribute__((ext_vector_type(4)));

#define CB   16    // batch B
#define TT   8     // temporal length
#define CIN  1024  // C
#define ICH  512   // IC
#define HWS  196   // H*W
#define NCOLS 1568 // TT*HWS
#define NT   13    // ceil(1568/128)

// ---------------- prep: weights -> bf16, fold 4 depthwise convs into one 7-tap ----------------
__global__ void k_prep_weights(const float* __restrict__ w1, const float* __restrict__ w2,
    const float* __restrict__ wb1, const float* __restrict__ bb1,
    const float* __restrict__ wb2, const float* __restrict__ bb2,
    const float* __restrict__ wb3, const float* __restrict__ bb3,
    const float* __restrict__ wb4, const float* __restrict__ bb4,
    __hip_bfloat16* __restrict__ w1b, __hip_bfloat16* __restrict__ w2b,
    float* __restrict__ weff, float* __restrict__ beff) {
  int idx = blockIdx.x * 256 + threadIdx.x;
  if (idx < CIN * ICH) {
    w1b[idx] = __float2bfloat16(w1[idx]);
    w2b[idx] = __float2bfloat16(w2[idx]);
  }
  if (idx < ICH) {
    float e[7];
#pragma unroll
    for (int u = 0; u < 7; u++) e[u] = wb4[idx * 7 + u];
#pragma unroll
    for (int u = 0; u < 5; u++) e[u + 1] += wb3[idx * 5 + u];
#pragma unroll
    for (int u = 0; u < 3; u++) e[u + 2] += wb2[idx * 3 + u];
    e[3] += wb1[idx];
#pragma unroll
    for (int u = 0; u < 7; u++) weff[idx * 8 + u] = e[u];
    weff[idx * 8 + 7] = 0.f;
    beff[idx] = bb1[idx] + bb2[idx] + bb3[idx] + bb4[idx];
  }
}

// ---------------- prep: x (BT,C,HW) fp32 -> xbT[b][n=hw*8+t][c] bf16 (transpose via LDS) ----------------
__global__ void k_prep_x(const float* __restrict__ x, __hip_bfloat16* __restrict__ xbT) {
  __shared__ float tile[64][50];
  int bid = blockIdx.x;
  int ht = bid & 3;          // 4 hw-tiles of 49
  int ct = (bid >> 2) & 15;  // 16 c-tiles of 64
  int t  = (bid >> 6) & 7;
  int b  = bid >> 9;
  int c0 = ct * 64, h0 = ht * 49;
  const float* src = x + ((size_t)((b * TT + t) * CIN + c0)) * HWS + h0;
  for (int idx = threadIdx.x; idx < 64 * 49; idx += 256) {
    int r = idx / 49, q = idx - r * 49;
    tile[r][q] = src[(size_t)r * HWS + q];
  }
  __syncthreads();
  for (int idx = threadIdx.x; idx < 49 * 64; idx += 256) {
    int h = idx >> 6, cc = idx & 63;
    size_t n1 = (size_t)(h0 + h) * TT + t;
    xbT[((size_t)b * NCOLS + n1) * CIN + (c0 + cc)] = __float2bfloat16(tile[cc][h]);
  }
}

// ---------------- GEMM: out[m][n] = sum_k A[m][k]*Bm[b][n][k], 128x128 tile, 16x16x32 bf16 MFMA ----------------
// EPI=0: out = z fp32 [b][m(=IC)][n] + bias  (conv1 output incl. b1)
// EPI=1: out = d_out fp32 [(b*8+t)*C+m][hw] = acc + bias + x residual
template <int KD, int MT, int EPI>
__global__ __launch_bounds__(256) void k_gemm(
    const __hip_bfloat16* __restrict__ A,   // [MT*128][KD] row-major
    const __hip_bfloat16* __restrict__ Bm,  // [b][NCOLS][KD] row-major in k
    const float* __restrict__ bias,
    const float* __restrict__ xres,
    float* __restrict__ out) {
  __shared__ __hip_bfloat16 As[128][40];
  __shared__ __hip_bfloat16 Bs[128][40];
  int bid = blockIdx.x;
  int nt = bid % NT;
  int mt = (bid / NT) % MT;
  int b  = bid / (NT * MT);
  int m0 = mt * 128, n0 = nt * 128;
  int tid = threadIdx.x;
  int lane = tid & 63;
  int wid = tid >> 6;
  int wm = wid >> 1, wn = wid & 1;   // 2x2 waves, each 64x64
  int lm = lane >> 4, ln = lane & 15;

  const __hip_bfloat16* Ag = A + (size_t)m0 * KD;
  const __hip_bfloat16* Bg = Bm + (size_t)b * NCOLS * KD;

  int arow = tid >> 2;          // 0..63
  int koff = (tid & 3) * 8;     // bf16 elements within BK=32

  f32x4 acc[4][4];
#pragma unroll
  for (int mf = 0; mf < 4; mf++)
#pragma unroll
    for (int nf = 0; nf < 4; nf++) acc[mf][nf] = (f32x4){0.f, 0.f, 0.f, 0.f};

  for (int ks = 0; ks < KD / 32; ks++) {
    int k0 = ks * 32;
    uint4 av0 = *(const uint4*)(Ag + (size_t)(arow) * KD + k0 + koff);
    uint4 av1 = *(const uint4*)(Ag + (size_t)(arow + 64) * KD + k0 + koff);
    int br0 = min(n0 + arow, NCOLS - 1);
    int br1 = min(n0 + arow + 64, NCOLS - 1);
    uint4 bv0 = *(const uint4*)(Bg + (size_t)br0 * KD + k0 + koff);
    uint4 bv1 = *(const uint4*)(Bg + (size_t)br1 * KD + k0 + koff);
    __syncthreads();
    *(uint4*)&As[arow][koff] = av0;
    *(uint4*)&As[arow + 64][koff] = av1;
    *(uint4*)&Bs[arow][koff] = bv0;
    *(uint4*)&Bs[arow + 64][koff] = bv1;
    __syncthreads();
    short8 af[4], bf[4];
#pragma unroll
    for (int mf = 0; mf < 4; mf++)
      af[mf] = *(const short8*)&As[wm * 64 + mf * 16 + ln][lm * 8];
#pragma unroll
    for (int nf = 0; nf < 4; nf++)
      bf[nf] = *(const short8*)&Bs[wn * 64 + nf * 16 + ln][lm * 8];
#pragma unroll
    for (int mf = 0; mf < 4; mf++)
#pragma unroll
      for (int nf = 0; nf < 4; nf++)
        acc[mf][nf] = __builtin_amdgcn_mfma_f32_16x16x32_bf16(af[mf], bf[nf], acc[mf][nf], 0, 0, 0);
  }

#pragma unroll
  for (int mf = 0; mf < 4; mf++) {
    int mrow = m0 + wm * 64 + mf * 16 + lm * 4;
#pragma unroll
    for (int nf = 0; nf < 4; nf++) {
      int n = n0 + wn * 64 + nf * 16 + ln;
      if (n < NCOLS) {
#pragma unroll
        for (int j = 0; j < 4; j++) {
          int o = mrow + j;
          float v = acc[mf][nf][j] + bias[o];
          if (EPI == 0) {
            out[((size_t)b * ICH + o) * NCOLS + n] = v;
          } else {
            int t = n / HWS;
            int hw = n - t * HWS;
            size_t oa = ((size_t)((b * TT + t) * CIN) + o) * HWS + hw;
            out[oa] = v + xres[oa];
          }
        }
      }
    }
  }
}

// ---------------- 7-tap temporal conv: z[b][i][hw*8+t] fp32 -> dwT[b][t*196+hw][i] bf16 ----------------
__global__ void k_conv(const float* __restrict__ z, const float* __restrict__ weff,
                       const float* __restrict__ beff, __hip_bfloat16* __restrict__ dwT) {
  int bid = blockIdx.x;  // b*HWS + hw
  int hw = bid % HWS;
  int b  = bid / HWS;
  int tid = threadIdx.x;
#pragma unroll
  for (int half = 0; half < 2; half++) {
    int i = tid + half * 256;
    const float* zp = z + ((size_t)(b * ICH + i) * NCOLS + hw * TT);
    float4 za = *(const float4*)zp;
    float4 zb = *(const float4*)(zp + 4);
    float zt[8] = {za.x, za.y, za.z, za.w, zb.x, zb.y, zb.z, zb.w};
    float e[7];
#pragma unroll
    for (int u = 0; u < 7; u++) e[u] = weff[i * 8 + u];
    float be = beff[i];
#pragma unroll
    for (int t = 0; t < TT; t++) {
      float s = be;
#pragma unroll
      for (int u = 0; u < 7; u++) {
        int tt = t + u - 3;
        if (tt >= 0 && tt < TT) s += e[u] * zt[tt];
      }
      dwT[((size_t)b * NCOLS + (t * HWS + hw)) * ICH + i] = __float2bfloat16(s);
    }
  }
}

extern "C" void kernel_launch(void* const* d_in, const int* in_sizes, int n_in,
                              void* d_out, int out_size, void* d_ws, size_t ws_size,
                              hipStream_t stream) {
  const float* x   = (const float*)d_in[0];
  const float* w1  = (const float*)d_in[1];
  const float* b1  = (const float*)d_in[2];
  const float* wb1 = (const float*)d_in[3];
  const float* bb1 = (const float*)d_in[4];
  const float* wb2 = (const float*)d_in[5];
  const float* bb2 = (const float*)d_in[6];
  const float* wb3 = (const float*)d_in[7];
  const float* bb3 = (const float*)d_in[8];
  const float* wb4 = (const float*)d_in[9];
  const float* bb4 = (const float*)d_in[10];
  const float* w2  = (const float*)d_in[11];
  const float* b2  = (const float*)d_in[12];
  float* out = (float*)d_out;

  // d_out doubles as scratch before the final GEMM overwrites it:
  //   floats [0, 12.845M)  : z fp32 (conv1 output)        = 51,380,224 B
  //   then 25.69M bf16     : xbT (transposed bf16 input)  = 51,380,224 B  (exactly fills d_out)
  float* z = out;
  __hip_bfloat16* xbT = (__hip_bfloat16*)(out + (size_t)CB * ICH * NCOLS);

  // ws: dwT (25.69 MB) + w1b (1 MB) + w2b (1 MB) + weff + beff
  char* ws = (char*)d_ws;
  __hip_bfloat16* dwT = (__hip_bfloat16*)ws;
  __hip_bfloat16* w1b = (__hip_bfloat16*)(ws + 25690112);
  __hip_bfloat16* w2b = (__hip_bfloat16*)(ws + 25690112 + 1048576);
  float* weff = (float*)(ws + 25690112 + 2097152);
  float* beff = (float*)(ws + 25690112 + 2097152 + 16384);

  k_prep_weights<<<(CIN * ICH + 255) / 256, 256, 0, stream>>>(
      w1, w2, wb1, bb1, wb2, bb2, wb3, bb3, wb4, bb4, w1b, w2b, weff, beff);
  k_prep_x<<<CB * TT * 16 * 4, 256, 0, stream>>>(x, xbT);
  k_gemm<1024, 4, 0><<<CB * 4 * NT, 256, 0, stream>>>(w1b, xbT, b1, nullptr, z);
  k_conv<<<CB * HWS, 256, 0, stream>>>(z, weff, beff, dwT);
  k_gemm<512, 8, 1><<<CB * 8 * NT, 256, 0, stream>>>(w2b, dwT, b2, x, out);
}

// Round 2
// 182.492 us; speedup vs baseline: 1.2484x; 1.2484x over previous
//
#include <hip/hip_runtime.h>
#include <hip/hip_bf16.h>

typedef short short8 __attribute__((ext_vector_type(8)));
typedef float f32x4 __attribute__((ext_vector_type(4)));
typedef unsigned int uint;

#define CB   16
#define TT   8
#define CIN  1024
#define ICH  512
#define HWS  196
#define NPB  1568   // cols per batch (196*8)
#define NF   25088  // flat cols = 16*1568 = 196*128 exactly
#define RT_N 196    // 128-tiles over NF

static __device__ __forceinline__ float bf2f(unsigned short u) {
  uint t = ((uint)u) << 16; float f; __builtin_memcpy(&f, &t, 4); return f;
}
static __device__ __forceinline__ unsigned short f2bf(float f) {
  __hip_bfloat16 h = __float2bfloat16(f); unsigned short u; __builtin_memcpy(&u, &h, 2); return u;
}

// async global->LDS, 16B per lane; LDS dest is wave-uniform base + lane*16
static __device__ __forceinline__ void stage16(const void* g, void* l) {
  __builtin_amdgcn_global_load_lds(
      (const __attribute__((address_space(1))) unsigned int*)(unsigned long long)g,
      (__attribute__((address_space(3))) unsigned int*)(unsigned int)(unsigned long long)l,
      16, 0, 0);
}

// ---------------- prep: weights -> bf16, fold 4 depthwise convs into one 7-tap ----------------
__global__ void k_prep_weights(const float* __restrict__ w1, const float* __restrict__ w2,
    const float* __restrict__ wb1, const float* __restrict__ bb1,
    const float* __restrict__ wb2, const float* __restrict__ bb2,
    const float* __restrict__ wb3, const float* __restrict__ bb3,
    const float* __restrict__ wb4, const float* __restrict__ bb4,
    __hip_bfloat16* __restrict__ w1b, __hip_bfloat16* __restrict__ w2b,
    float* __restrict__ weff, float* __restrict__ beff) {
  int idx = blockIdx.x * 256 + threadIdx.x;
  if (idx < CIN * ICH) {
    w1b[idx] = __float2bfloat16(w1[idx]);
    w2b[idx] = __float2bfloat16(w2[idx]);
  }
  if (idx < ICH) {
    float e[7];
#pragma unroll
    for (int u = 0; u < 7; u++) e[u] = wb4[idx * 7 + u];
#pragma unroll
    for (int u = 0; u < 5; u++) e[u + 1] += wb3[idx * 5 + u];
#pragma unroll
    for (int u = 0; u < 3; u++) e[u + 2] += wb2[idx * 3 + u];
    e[3] += wb1[idx];
#pragma unroll
    for (int u = 0; u < 7; u++) weff[idx * 8 + u] = e[u];
    weff[idx * 8 + 7] = 0.f;
    beff[idx] = bb1[idx] + bb2[idx] + bb3[idx] + bb4[idx];
  }
}

// ---------------- prep: x (BT,C,HW) fp32 -> xbT[n=(b,hw,t)][c] bf16 ----------------
__global__ void k_prep_x(const float* __restrict__ x, __hip_bfloat16* __restrict__ xbT) {
  __shared__ float tile[64][51];
  int bid = blockIdx.x;
  int ht = bid & 3;          // 4 hw-tiles of 49
  int ct = (bid >> 2) & 15;  // 16 c-tiles of 64
  int t  = (bid >> 6) & 7;
  int b  = bid >> 9;
  int c0 = ct * 64, h0 = ht * 49;
  const float* src = x + ((size_t)((b * TT + t) * CIN + c0)) * HWS + h0;
  for (int idx = threadIdx.x; idx < 64 * 49; idx += 256) {
    int r = idx / 49, q = idx - r * 49;
    tile[r][q] = src[(size_t)r * HWS + q];
  }
  __syncthreads();
  for (int idx = threadIdx.x; idx < 49 * 16; idx += 256) {
    int h = idx >> 4, g = idx & 15;
    ushort4 pk;
    pk.x = f2bf(tile[g * 4 + 0][h]);
    pk.y = f2bf(tile[g * 4 + 1][h]);
    pk.z = f2bf(tile[g * 4 + 2][h]);
    pk.w = f2bf(tile[g * 4 + 3][h]);
    size_t n1 = (size_t)(h0 + h) * TT + t;
    *(ushort4*)&xbT[((size_t)b * NPB + n1) * CIN + (c0 + g * 4)] = pk;
  }
}

// ---------------- shared GEMM core: 128x128 tile, BK=32, global_load_lds staging ----------------
// D rows (lm*4+j side) come from Ar rows; D cols (ln side) come from Br rows.
template <int KD>
static __device__ __forceinline__ void gemm_core(
    const __hip_bfloat16* __restrict__ Ar,  // 128 rows x KD (k-contiguous)
    const __hip_bfloat16* __restrict__ Br,  // 128 rows x KD
    __hip_bfloat16* As, __hip_bfloat16* Bs, f32x4 (&acc)[4][4]) {
  int tid = threadIdx.x;
  int lane = tid & 63, w = tid >> 6;
  int wm = w >> 1, wn = w & 1, ln = lane & 15, lm = lane >> 4;
  int rseg = lane >> 2;        // 0..15 row within 16-row segment
  int kb = (lane & 3) * 8;     // bf16 offset within BK=32
  const __hip_bfloat16* ga0 = Ar + (size_t)(w * 32 + rseg) * KD + kb;
  const __hip_bfloat16* ga1 = ga0 + (size_t)16 * KD;
  const __hip_bfloat16* gb0 = Br + (size_t)(w * 32 + rseg) * KD + kb;
  const __hip_bfloat16* gb1 = gb0 + (size_t)16 * KD;
  __hip_bfloat16* la0 = As + w * 1024;
  __hip_bfloat16* la1 = As + w * 1024 + 512;
  __hip_bfloat16* lb0 = Bs + w * 1024;
  __hip_bfloat16* lb1 = Bs + w * 1024 + 512;
  for (int ks = 0; ks < KD / 32; ks++) {
    int k0 = ks * 32;
    stage16(ga0 + k0, la0);
    stage16(ga1 + k0, la1);
    stage16(gb0 + k0, lb0);
    stage16(gb1 + k0, lb1);
    __syncthreads();  // drains vmcnt -> LDS tile ready
    short8 af[4], bf[4];
#pragma unroll
    for (int mf = 0; mf < 4; mf++)
      af[mf] = *(const short8*)&As[(wm * 64 + mf * 16 + ln) * 32 + lm * 8];
#pragma unroll
    for (int nf = 0; nf < 4; nf++)
      bf[nf] = *(const short8*)&Bs[(wn * 64 + nf * 16 + ln) * 32 + lm * 8];
#pragma unroll
    for (int mf = 0; mf < 4; mf++)
#pragma unroll
      for (int nf = 0; nf < 4; nf++)
        acc[mf][nf] = __builtin_amdgcn_mfma_f32_16x16x32_bf16(af[mf], bf[nf], acc[mf][nf], 0, 0, 0);
    __syncthreads();  // protect LDS before next stage overwrites
  }
}

// ---------------- GEMM1: zT[n][o] = xbT[n][:] . w1b[o][:] + b1[o], bf16 out ----------------
__global__ __launch_bounds__(256) void k_gemm1(const __hip_bfloat16* __restrict__ xbT,
                                               const __hip_bfloat16* __restrict__ w1b,
                                               const float* __restrict__ b1,
                                               __hip_bfloat16* __restrict__ zb) {
  __shared__ __hip_bfloat16 As[128 * 32], Bs[128 * 32];
  int xcd = blockIdx.x & 7, i = blockIdx.x >> 3;
  int rt = xcd * 25 + (i >> 2);  // n-tile; 4 o-tiles sharing it land on same XCD
  if (rt >= RT_N) return;
  int ot = i & 3;
  int n0 = rt * 128, o0 = ot * 128;
  f32x4 acc[4][4];
#pragma unroll
  for (int a = 0; a < 4; a++)
#pragma unroll
    for (int c = 0; c < 4; c++) acc[a][c] = (f32x4){0.f, 0.f, 0.f, 0.f};
  gemm_core<1024>(xbT + (size_t)n0 * CIN, w1b + (size_t)o0 * CIN, As, Bs, acc);
  int tid = threadIdx.x, lane = tid & 63, w = tid >> 6;
  int wm = w >> 1, wn = w & 1, ln = lane & 15, lm = lane >> 4;
#pragma unroll
  for (int nf = 0; nf < 4; nf++) {
    int o = o0 + wn * 64 + nf * 16 + ln;
    float bo = b1[o];
#pragma unroll
    for (int mf = 0; mf < 4; mf++) {
      int nr = n0 + wm * 64 + mf * 16 + lm * 4;
#pragma unroll
      for (int j = 0; j < 4; j++)
        zb[(size_t)(nr + j) * ICH + o] = __float2bfloat16(acc[mf][nf][j] + bo);
    }
  }
}

// ---------------- conv: zb[n][o] -> dwT[n2=(b, t*196+hw)][o], 7-tap along t ----------------
__global__ void k_conv(const __hip_bfloat16* __restrict__ zb, const float* __restrict__ weff,
                       const float* __restrict__ beff, __hip_bfloat16* __restrict__ dwT) {
  int bid = blockIdx.x;  // b*HWS + hw
  int hw = bid % HWS, b = bid / HWS;
  int o = threadIdx.x * 2;
  size_t nb = (size_t)b * NPB + hw * TT;
  float z0[TT], z1[TT];
#pragma unroll
  for (int t = 0; t < TT; t++) {
    uint v = *(const uint*)&zb[(nb + t) * ICH + o];
    z0[t] = bf2f((unsigned short)(v & 0xffff));
    z1[t] = bf2f((unsigned short)(v >> 16));
  }
  float e0[7], e1[7];
#pragma unroll
  for (int u = 0; u < 7; u++) { e0[u] = weff[o * 8 + u]; e1[u] = weff[(o + 1) * 8 + u]; }
  float be0 = beff[o], be1 = beff[o + 1];
#pragma unroll
  for (int t = 0; t < TT; t++) {
    float s0 = be0, s1 = be1;
#pragma unroll
    for (int u = 0; u < 7; u++) {
      int tt = t + u - 3;
      if (tt >= 0 && tt < TT) { s0 += e0[u] * z0[tt]; s1 += e1[u] * z1[tt]; }
    }
    uint pk = ((uint)f2bf(s1) << 16) | f2bf(s0);
    *(uint*)&dwT[((size_t)b * NPB + t * HWS + hw) * ICH + o] = pk;
  }
}

// ---------------- GEMM2: out[o2][n2] = w2b[o2][:] . dwT[n2][:] + b2 + residual ----------------
__global__ __launch_bounds__(256) void k_gemm2(const __hip_bfloat16* __restrict__ dwT,
                                               const __hip_bfloat16* __restrict__ w2b,
                                               const float* __restrict__ b2,
                                               const float* __restrict__ xres,
                                               float* __restrict__ out) {
  __shared__ __hip_bfloat16 As[128 * 32], Bs[128 * 32];
  int xcd = blockIdx.x & 7, i = blockIdx.x >> 3;
  int nt = xcd * 25 + (i >> 3);  // n-tile; 8 m-tiles sharing it land on same XCD
  if (nt >= RT_N) return;
  int mt = i & 7;
  int n0 = nt * 128, m0 = mt * 128;
  f32x4 acc[4][4];
#pragma unroll
  for (int a = 0; a < 4; a++)
#pragma unroll
    for (int c = 0; c < 4; c++) acc[a][c] = (f32x4){0.f, 0.f, 0.f, 0.f};
  gemm_core<512>(w2b + (size_t)m0 * ICH, dwT + (size_t)n0 * ICH, As, Bs, acc);
  int tid = threadIdx.x, lane = tid & 63, w = tid >> 6;
  int wm = w >> 1, wn = w & 1, ln = lane & 15, lm = lane >> 4;
#pragma unroll
  for (int nf = 0; nf < 4; nf++) {
    int n2f = n0 + wn * 64 + nf * 16 + ln;
    int b = n2f / NPB;
    int r = n2f - b * NPB;
    int t = r / HWS;
    int hw = r - t * HWS;
    size_t colbase = (size_t)((b * TT + t) * CIN) * HWS + hw;
#pragma unroll
    for (int mf = 0; mf < 4; mf++) {
      int o2b = m0 + wm * 64 + mf * 16 + lm * 4;
#pragma unroll
      for (int j = 0; j < 4; j++) {
        int o2 = o2b + j;
        size_t a = colbase + (size_t)o2 * HWS;
        out[a] = acc[mf][nf][j] + b2[o2] + xres[a];
      }
    }
  }
}

extern "C" void kernel_launch(void* const* d_in, const int* in_sizes, int n_in,
                              void* d_out, int out_size, void* d_ws, size_t ws_size,
                              hipStream_t stream) {
  const float* x   = (const float*)d_in[0];
  const float* w1  = (const float*)d_in[1];
  const float* b1  = (const float*)d_in[2];
  const float* wb1 = (const float*)d_in[3];
  const float* bb1 = (const float*)d_in[4];
  const float* wb2 = (const float*)d_in[5];
  const float* bb2 = (const float*)d_in[6];
  const float* wb3 = (const float*)d_in[7];
  const float* bb3 = (const float*)d_in[8];
  const float* wb4 = (const float*)d_in[9];
  const float* bb4 = (const float*)d_in[10];
  const float* w2  = (const float*)d_in[11];
  const float* b2  = (const float*)d_in[12];
  float* out = (float*)d_out;

  // d_out as scratch (102.76MB total):
  //   bytes [0, 25.69M):        zb  bf16 [NF][ICH]   (dead after k_conv)
  //   bytes [51.38M, 102.76M):  xbT bf16 [NF][CIN]   (dead after k_gemm1)
  __hip_bfloat16* zb  = (__hip_bfloat16*)d_out;
  __hip_bfloat16* xbT = (__hip_bfloat16*)((char*)d_out + 51380224);

  // ws: dwT 25.69MB + w1b 1MB + w2b 1MB + weff 16KB + beff 2KB  (~27.7MB)
  char* ws = (char*)d_ws;
  __hip_bfloat16* dwT = (__hip_bfloat16*)ws;
  __hip_bfloat16* w1b = (__hip_bfloat16*)(ws + 25690112);
  __hip_bfloat16* w2b = (__hip_bfloat16*)(ws + 25690112 + 1048576);
  float* weff = (float*)(ws + 25690112 + 2097152);
  float* beff = weff + 4096;

  k_prep_weights<<<(CIN * ICH + 255) / 256, 256, 0, stream>>>(
      w1, w2, wb1, bb1, wb2, bb2, wb3, bb3, wb4, bb4, w1b, w2b, weff, beff);
  k_prep_x<<<CB * TT * 16 * 4, 256, 0, stream>>>(x, xbT);
  k_gemm1<<<8 * 25 * 4, 256, 0, stream>>>(xbT, w1b, b1, zb);
  k_conv<<<CB * HWS, 256, 0, stream>>>(zb, weff, beff, dwT);
  k_gemm2<<<8 * 25 * 8, 256, 0, stream>>>(dwT, w2b, b2, x, out);
}